// Round 3
// baseline (368.276 us; speedup 1.0000x reference)
//
#include <hip/hip_runtime.h>

// Problem constants (B, C, CI, H, W) = (4, 256, 128, 64, 64)
constexpr int kB  = 4;
constexpr int kC  = 256;
constexpr int kCI = 128;
constexpr int kN  = 64 * 64;  // 4096

// ---------------------------------------------------------------------------
// Algebraic collapse (no gram, no pairwise):
//   Phi = phi_w*X, G2 = g_w*X                (CI x N each; stacked as PG)
//   T   = Phic*G2^T = Phi*G2^T - rsPhi*rsG2^T/N     (CI x CI per batch)
//   W2t = out_w * T^T                        (C x CI)
//   Mt  = W2t * theta_wc                     (C x C), theta_wc col-centered
//   beta= W2t * theta_bc + out_b
//   out[b,o,n] = x[b,o,n] + sum_c Mt[b,o,c]*x[b,c,n] + beta[b,o]
// g_b drops (rows of Phic sum to 0); phi_b drops (spatial centering).
// T computed via two-stage split-K (plain stores + reduce; NO dense atomics —
// round-2's 4.19M atomicAdds onto 64 KB serialized at 197 us).
// ---------------------------------------------------------------------------

constexpr int kSplits = 64;

// ws layout (floats)
constexpr long kOffTwcT  = 0;                            // kC*kCI         = 32768
constexpr long kOffTbc   = kOffTwcT + kC * kCI;          // kCI            = 128
constexpr long kOffPG    = kOffTbc + kCI;                // kB*kC*kN       = 4194304
constexpr long kOffRs    = kOffPG + (long)kB * kC * kN;  // kB*kC          = 1024
constexpr long kOffTpart = kOffRs + kB * kC;             // kB*kSplits*kCI*kCI = 4194304
constexpr long kOffT     = kOffTpart + (long)kB * kSplits * kCI * kCI; // kB*kCI*kCI = 65536
constexpr long kOffW2t   = kOffT + kB * kCI * kCI;       // kB*kC*kCI      = 131072
constexpr long kOffMt    = kOffW2t + kB * kC * kCI;      // kB*kC*kC       = 262144
constexpr long kOffBeta  = kOffMt + kB * kC * kC;        // kB*kC          = 1024
// total ~8.9M floats = 35.5 MB of d_ws

// ---- theta_w column-centered (transposed) + theta_b centered --------------
__global__ void centerw_kernel(const float* __restrict__ theta_w,
                               const float* __restrict__ theta_b,
                               float* __restrict__ twcT, float* __restrict__ tbc) {
    __shared__ float sm[128];
    int t = threadIdx.x;  // 256 threads, one column of theta_w each
    if (t < 128) sm[t] = theta_b[t];
    __syncthreads();
    for (int st = 64; st > 0; st >>= 1) {
        if (t < st) sm[t] += sm[t + st];
        __syncthreads();
    }
    float bmean = sm[0] * (1.f / kCI);
    float m = 0.f;
    for (int k = 0; k < kCI; k++) m += theta_w[k * kC + t];
    m *= (1.f / kCI);
    for (int k = 0; k < kCI; k++) twcT[t * kCI + k] = theta_w[k * kC + t] - m;
    if (t < 128) tbc[t] = theta_b[t] - bmean;
}

// ---- PG[b][r][n]: r<128 -> phi_w row r; r>=128 -> g_w row r-128 -----------
// 128(M) x 64(N) tile, 256 threads, 8x4 per thread, K=kC in chunks of 16.
__global__ void pg_gemm(const float* __restrict__ phi_w, const float* __restrict__ g_w,
                        const float* __restrict__ x, float* __restrict__ PG) {
    int b = blockIdx.z;
    int m0 = blockIdx.y * 128, n0 = blockIdx.x * 64;
    __shared__ __align__(16) float Ws[16][136];  // [k][row]
    __shared__ __align__(16) float Xs[16][68];   // [k][col]
    int t = threadIdx.x;
    int tx = t & 15, ty = t >> 4;
    float acc[8][4] = {};
    const float* xb = x + (long)b * kC * kN;
    for (int kc = 0; kc < kC; kc += 16) {
        __syncthreads();
        {   // W tile: 128 rows x 16 cols
            int r = t >> 2, c4 = (t & 3) * 4;
#pragma unroll
            for (int i = 0; i < 2; i++) {
                int rr = r + 64 * i;
                int row = m0 + rr;
                const float* wr = (row < kCI) ? (phi_w + (long)row * kC)
                                              : (g_w + (long)(row - kCI) * kC);
                float4 v = *(const float4*)(wr + kc + c4);
                Ws[c4 + 0][rr] = v.x; Ws[c4 + 1][rr] = v.y;
                Ws[c4 + 2][rr] = v.z; Ws[c4 + 3][rr] = v.w;
            }
        }
        {   // X tile: 16 rows(k) x 64 cols
            int k = t >> 4, c4 = (t & 15) * 4;
            *(float4*)&Xs[k][c4] = *(const float4*)(xb + (long)(kc + k) * kN + n0 + c4);
        }
        __syncthreads();
#pragma unroll
        for (int k = 0; k < 16; k++) {
            float4 a0 = *(const float4*)&Ws[k][8 * ty];
            float4 a1 = *(const float4*)&Ws[k][8 * ty + 4];
            float4 bv = *(const float4*)&Xs[k][4 * tx];
            float av[8] = {a0.x, a0.y, a0.z, a0.w, a1.x, a1.y, a1.z, a1.w};
            float bw[4] = {bv.x, bv.y, bv.z, bv.w};
#pragma unroll
            for (int i = 0; i < 8; i++)
#pragma unroll
                for (int j = 0; j < 4; j++) acc[i][j] += av[i] * bw[j];
        }
    }
    float* pb = PG + (long)b * kC * kN;
#pragma unroll
    for (int i = 0; i < 8; i++) {
        int row = m0 + ty * 8 + i;
        float4 ov = {acc[i][0], acc[i][1], acc[i][2], acc[i][3]};
        *(float4*)(pb + (long)row * kN + n0 + tx * 4) = ov;
    }
}

// ---- Tpart[b][s] = Phi[:, slice] * G2[:, slice]^T  (128x128 per slice) ----
// Also accumulates row-sum partials of Phi/G2 into rs (tiny atomics, 64K total).
__global__ void tsplit_kernel(const float* __restrict__ PG, float* __restrict__ Tpart,
                              float* __restrict__ rs) {
    int s = blockIdx.x, b = blockIdx.z;
    int mbase = s * (kN / kSplits);  // 64 m's per slice
    __shared__ __align__(16) float As[16][136];  // [m][c]   (Phi rows)
    __shared__ __align__(16) float Bs[16][136];  // [m][c']  (G2 rows)
    int t = threadIdx.x;
    int tx = t & 15, ty = t >> 4;
    float acc[8][8] = {};
    float rsA[8] = {};  // used by tx==0 threads: row sums of Phi rows 8ty..
    float rsB[8] = {};  // used by ty==0 threads: row sums of G2 rows 8tx..
    const float* Phi = PG + (long)b * kC * kN;                   // rows 0..127
    const float* G2  = PG + (long)b * kC * kN + (long)kCI * kN;  // rows 128..255
    for (int mc = 0; mc < kN / kSplits; mc += 16) {
        __syncthreads();
        {   // each operand: 128 rows x 16 m
            int r = t >> 2, c4 = (t & 3) * 4;
#pragma unroll
            for (int i = 0; i < 2; i++) {
                int rr = r + 64 * i;
                float4 va = *(const float4*)(Phi + (long)rr * kN + mbase + mc + c4);
                As[c4 + 0][rr] = va.x; As[c4 + 1][rr] = va.y;
                As[c4 + 2][rr] = va.z; As[c4 + 3][rr] = va.w;
                float4 vb = *(const float4*)(G2 + (long)rr * kN + mbase + mc + c4);
                Bs[c4 + 0][rr] = vb.x; Bs[c4 + 1][rr] = vb.y;
                Bs[c4 + 2][rr] = vb.z; Bs[c4 + 3][rr] = vb.w;
            }
        }
        __syncthreads();
#pragma unroll
        for (int k = 0; k < 16; k++) {
            float4 a0 = *(const float4*)&As[k][8 * ty];
            float4 a1 = *(const float4*)&As[k][8 * ty + 4];
            float4 b0 = *(const float4*)&Bs[k][8 * tx];
            float4 b1 = *(const float4*)&Bs[k][8 * tx + 4];
            float av[8] = {a0.x, a0.y, a0.z, a0.w, a1.x, a1.y, a1.z, a1.w};
            float bw[8] = {b0.x, b0.y, b0.z, b0.w, b1.x, b1.y, b1.z, b1.w};
#pragma unroll
            for (int i = 0; i < 8; i++)
#pragma unroll
                for (int j = 0; j < 8; j++) acc[i][j] += av[i] * bw[j];
            if (tx == 0)
#pragma unroll
                for (int i = 0; i < 8; i++) rsA[i] += av[i];
            if (ty == 0)
#pragma unroll
                for (int j = 0; j < 8; j++) rsB[j] += bw[j];
        }
    }
    float* Tp = Tpart + ((long)b * kSplits + s) * kCI * kCI;
#pragma unroll
    for (int i = 0; i < 8; i++) {
        int c = ty * 8 + i;
#pragma unroll
        for (int j = 0; j < 2; j++) {
            float4 ov = {acc[i][4 * j], acc[i][4 * j + 1], acc[i][4 * j + 2], acc[i][4 * j + 3]};
        *(float4*)(Tp + (long)c * kCI + tx * 8 + 4 * j) = ov;
        }
    }
    if (tx == 0)
#pragma unroll
        for (int i = 0; i < 8; i++) atomicAdd(rs + b * kC + ty * 8 + i, rsA[i]);
    if (ty == 0)
#pragma unroll
        for (int j = 0; j < 8; j++) atomicAdd(rs + b * kC + kCI + tx * 8 + j, rsB[j]);
}

// ---- T[b] = sum_s Tpart[b][s] - rsPhi*rsG2^T/N ----------------------------
__global__ void treduce_kernel(const float* __restrict__ Tpart, const float* __restrict__ rs,
                               float* __restrict__ T) {
    int idx = blockIdx.x * 256 + threadIdx.x;  // 0 .. kB*kCI*kCI-1
    int b = idx >> 14;
    int c = (idx >> 7) & 127, cp = idx & 127;
    const float* tp = Tpart + (long)b * kSplits * kCI * kCI + (idx & 16383);
    float s = 0.f;
#pragma unroll 8
    for (int sl = 0; sl < kSplits; sl++) s += tp[(long)sl * kCI * kCI];
    s -= rs[b * kC + c] * rs[b * kC + kCI + cp] * (1.f / kN);
    T[idx] = s;
}

// ---- NT gemm, 64x64 tile, 4x4/thread: C[b][m][n] = sum_k A[b][m][k]*B[b][n][k]
__global__ void nt64_gemm(const float* __restrict__ A, const float* __restrict__ B,
                          float* __restrict__ Cm, int M, int N, int K,
                          long sA, long sB, long sC) {
    int b = blockIdx.z;
    const float* Ab = A + (long)b * sA;
    const float* Bb = B + (long)b * sB;
    float* Cb = Cm + (long)b * sC;
    __shared__ __align__(16) float As[16][68];  // [k][row]
    __shared__ __align__(16) float Bs[16][68];
    int t = threadIdx.x;
    int tx = t & 15, ty = t >> 4;
    int m0 = blockIdx.y * 64, n0 = blockIdx.x * 64;
    float acc[4][4] = {};
    for (int kc = 0; kc < K; kc += 16) {
        __syncthreads();
        {
            int r = t >> 2, c4 = (t & 3) * 4;
            float4 va = *(const float4*)(Ab + (long)(m0 + r) * K + kc + c4);
            As[c4 + 0][r] = va.x; As[c4 + 1][r] = va.y;
            As[c4 + 2][r] = va.z; As[c4 + 3][r] = va.w;
            float4 vb = *(const float4*)(Bb + (long)(n0 + r) * K + kc + c4);
            Bs[c4 + 0][r] = vb.x; Bs[c4 + 1][r] = vb.y;
            Bs[c4 + 2][r] = vb.z; Bs[c4 + 3][r] = vb.w;
        }
        __syncthreads();
#pragma unroll
        for (int k = 0; k < 16; k++) {
            float4 a = *(const float4*)&As[k][4 * ty];
            float4 bv = *(const float4*)&Bs[k][4 * tx];
            float av[4] = {a.x, a.y, a.z, a.w};
            float bw[4] = {bv.x, bv.y, bv.z, bv.w};
#pragma unroll
            for (int i = 0; i < 4; i++)
#pragma unroll
                for (int j = 0; j < 4; j++) acc[i][j] += av[i] * bw[j];
        }
    }
#pragma unroll
    for (int i = 0; i < 4; i++) {
        float4 ov = {acc[i][0], acc[i][1], acc[i][2], acc[i][3]};
        *(float4*)(Cb + (long)(m0 + 4 * ty + i) * N + n0 + 4 * tx) = ov;
    }
}

// ---- beta[b,o] = out_b[o] + sum_k theta_bc[k] * W2t[b,o,k] ----------------
__global__ void beta_kernel(const float* __restrict__ W2t, const float* __restrict__ tbc,
                            const float* __restrict__ out_b, float* __restrict__ beta) {
    int i = blockIdx.x * blockDim.x + threadIdx.x;  // b*kC + o
    if (i >= kB * kC) return;
    int o = i & (kC - 1);
    float s = out_b[o];
    const float* row = W2t + (long)i * kCI;
#pragma unroll 8
    for (int k = 0; k < kCI; k++) s += tbc[k] * row[k];
    beta[i] = s;
}

// ---- out[b,o,n] = x[b,o,n] + sum_c Mt[b,o,c]*x[b,c,n] + beta[b,o] ---------
// 128(o) x 64(n) tile, 256 threads, 8x4 per thread, K=kC in chunks of 16.
__global__ void final_kernel(const float* __restrict__ x, const float* __restrict__ Mt,
                             const float* __restrict__ beta, float* __restrict__ out) {
    int b = blockIdx.z;
    int o0 = blockIdx.y * 128, n0 = blockIdx.x * 64;
    __shared__ __align__(16) float Ms[16][136];  // [k][o-row]
    __shared__ __align__(16) float Xs[16][68];   // [k][n-col]
    int t = threadIdx.x;
    int tx = t & 15, ty = t >> 4;
    float acc[8][4] = {};
    const float* xb = x + (long)b * kC * kN;
    const float* Mb = Mt + (long)b * kC * kC;
    for (int kc = 0; kc < kC; kc += 16) {
        __syncthreads();
        {   // Mt tile: 128 rows x 16 cols
            int r = t >> 2, c4 = (t & 3) * 4;
#pragma unroll
            for (int i = 0; i < 2; i++) {
                int rr = r + 64 * i;
                float4 v = *(const float4*)(Mb + (long)(o0 + rr) * kC + kc + c4);
                Ms[c4 + 0][rr] = v.x; Ms[c4 + 1][rr] = v.y;
                Ms[c4 + 2][rr] = v.z; Ms[c4 + 3][rr] = v.w;
            }
        }
        {   // X tile: 16 rows(ch) x 64 cols
            int k = t >> 4, c4 = (t & 15) * 4;
            *(float4*)&Xs[k][c4] = *(const float4*)(xb + (long)(kc + k) * kN + n0 + c4);
        }
        __syncthreads();
#pragma unroll
        for (int k = 0; k < 16; k++) {
            float4 a0 = *(const float4*)&Ms[k][8 * ty];
            float4 a1 = *(const float4*)&Ms[k][8 * ty + 4];
            float4 bv = *(const float4*)&Xs[k][4 * tx];
            float av[8] = {a0.x, a0.y, a0.z, a0.w, a1.x, a1.y, a1.z, a1.w};
            float bw[4] = {bv.x, bv.y, bv.z, bv.w};
#pragma unroll
            for (int i = 0; i < 8; i++)
#pragma unroll
                for (int j = 0; j < 4; j++) acc[i][j] += av[i] * bw[j];
        }
    }
#pragma unroll
    for (int i = 0; i < 8; i++) {
        int o = o0 + ty * 8 + i;
        float bt = beta[b * kC + o];
        long base = (long)b * kC * kN + (long)o * kN + n0 + tx * 4;
        float4 xv = *(const float4*)(x + base);
        float4 ov = {acc[i][0] + xv.x + bt, acc[i][1] + xv.y + bt,
                     acc[i][2] + xv.z + bt, acc[i][3] + xv.w + bt};
        *(float4*)(out + base) = ov;
    }
}

extern "C" void kernel_launch(void* const* d_in, const int* in_sizes, int n_in,
                              void* d_out, int out_size, void* d_ws, size_t ws_size,
                              hipStream_t stream) {
    const float* x       = (const float*)d_in[0];
    const float* g_w     = (const float*)d_in[1];
    // d_in[2] = g_b   : cancelled (rows of Phic sum to 0)
    const float* theta_w = (const float*)d_in[3];
    const float* theta_b = (const float*)d_in[4];
    const float* phi_w   = (const float*)d_in[5];
    // d_in[6] = phi_b : cancelled by spatial centering
    const float* out_w   = (const float*)d_in[7];
    const float* out_b   = (const float*)d_in[8];
    float* out = (float*)d_out;
    float* ws  = (float*)d_ws;  // needs ~35.5 MB

    float* twcT  = ws + kOffTwcT;
    float* tbc   = ws + kOffTbc;
    float* PG    = ws + kOffPG;
    float* rs    = ws + kOffRs;
    float* Tpart = ws + kOffTpart;
    float* T     = ws + kOffT;
    float* W2t   = ws + kOffW2t;
    float* Mt    = ws + kOffMt;
    float* beta  = ws + kOffBeta;

    hipMemsetAsync(rs, 0, (size_t)kB * kC * sizeof(float), stream);
    centerw_kernel<<<1, 256, 0, stream>>>(theta_w, theta_b, twcT, tbc);
    // PG[b] = [phi_w; g_w] * X[b]   (256 x 4096, K=256)
    pg_gemm<<<dim3(kN / 64, 2, kB), 256, 0, stream>>>(phi_w, g_w, x, PG);
    // Tpart[b][s] = Phi_slice * G2_slice^T  (+ row-sum partials into rs)
    tsplit_kernel<<<dim3(kSplits, 1, kB), 256, 0, stream>>>(PG, Tpart, rs);
    // T[b] = sum_s Tpart - rs outer correction
    treduce_kernel<<<kB * kCI * kCI / 256, 256, 0, stream>>>(Tpart, rs, T);
    // W2t[b] = out_w * T[b]^T       (M=256, N=128, K=128)
    nt64_gemm<<<dim3(2, 4, kB), 256, 0, stream>>>(out_w, T, W2t, kC, kCI, kCI,
                                                  0, (long)kCI * kCI, (long)kC * kCI);
    // Mt[b] = W2t[b] * theta_wc     (M=256, N=256, K=128)
    nt64_gemm<<<dim3(4, 4, kB), 256, 0, stream>>>(W2t, twcT, Mt, kC, kC, kCI,
                                                  (long)kC * kCI, 0, (long)kC * kC);
    beta_kernel<<<kB, 256, 0, stream>>>(W2t, tbc, out_b, beta);
    final_kernel<<<dim3(kN / 64, 2, kB), 256, 0, stream>>>(x, Mt, beta, out);
}

// Round 4
// 196.996 us; speedup vs baseline: 1.8695x; 1.8695x over previous
//
#include <hip/hip_runtime.h>

// Problem constants (B, C, CI, H, W) = (4, 256, 128, 64, 64)
constexpr int kB  = 4;
constexpr int kC  = 256;
constexpr int kCI = 128;
constexpr int kN  = 64 * 64;  // 4096

// ---------------------------------------------------------------------------
// Algebraic collapse (no gram, no pairwise):
//   Phi = phi_w*X, G2 = g_w*X                (CI x N each; stacked as PG)
//   T   = Phic*G2^T = Phi*G2^T - rsPhi*rsG2^T/N     (CI x CI per batch)
//   W2t = out_w * T^T                        (C x CI)
//   Mt  = W2t * theta_wc                     (C x C), theta_wc col-centered
//   beta= W2t * theta_bc + out_b
//   out[b,o,n] = x[b,o,n] + sum_c Mt[b,o,c]*x[b,c,n] + beta[b,o]
// g_b drops (rows of Phic sum to 0); phi_b drops (spatial centering).
//
// ROUND-4 FIX: rounds 2/3 spilled — acc[8][8]=64 floats vs VGPR_Count=64
// (compiler occupancy heuristic) => every FMA hit scratch (WRITE_SIZE 248 MB,
// VALUBusy 2%). ALL tile kernels now use 4x4 acc (16 VGPRs) + 64x64 tiles +
// __launch_bounds__(256,4); parallelism comes from more blocks, not bigger
// per-thread tiles.
// ---------------------------------------------------------------------------

constexpr int kSplits = 64;

// ws layout (floats)
constexpr long kOffTwcT  = 0;                            // kC*kCI         = 32768
constexpr long kOffTbc   = kOffTwcT + kC * kCI;          // kCI            = 128
constexpr long kOffPG    = kOffTbc + kCI;                // kB*kC*kN       = 4194304
constexpr long kOffRs    = kOffPG + (long)kB * kC * kN;  // kB*kC          = 1024
constexpr long kOffTpart = kOffRs + kB * kC;             // kB*kSplits*kCI*kCI = 4194304
constexpr long kOffT     = kOffTpart + (long)kB * kSplits * kCI * kCI; // 65536
constexpr long kOffW2t   = kOffT + kB * kCI * kCI;       // kB*kC*kCI      = 131072
constexpr long kOffMt    = kOffW2t + kB * kC * kCI;      // kB*kC*kC       = 262144
constexpr long kOffBeta  = kOffMt + kB * kC * kC;        // kB*kC          = 1024
// total ~8.9M floats = 35.5 MB of d_ws

// ---- theta_w column-centered (transposed) + theta_b centered --------------
__global__ void centerw_kernel(const float* __restrict__ theta_w,
                               const float* __restrict__ theta_b,
                               float* __restrict__ twcT, float* __restrict__ tbc) {
    __shared__ float sm[128];
    int t = threadIdx.x;  // 256 threads, one column of theta_w each
    if (t < 128) sm[t] = theta_b[t];
    __syncthreads();
    for (int st = 64; st > 0; st >>= 1) {
        if (t < st) sm[t] += sm[t + st];
        __syncthreads();
    }
    float bmean = sm[0] * (1.f / kCI);
    float m = 0.f;
    for (int k = 0; k < kCI; k++) m += theta_w[k * kC + t];
    m *= (1.f / kCI);
    for (int k = 0; k < kCI; k++) twcT[t * kCI + k] = theta_w[k * kC + t] - m;
    if (t < 128) tbc[t] = theta_b[t] - bmean;
}

// ---- PG[b][r][n]: r<128 -> phi_w row r; r>=128 -> g_w row r-128 -----------
// 64(M) x 64(N) tile, 256 threads, 4x4 per thread, K=kC in chunks of 16.
__global__ void __launch_bounds__(256, 4)
pg_gemm(const float* __restrict__ phi_w, const float* __restrict__ g_w,
        const float* __restrict__ x, float* __restrict__ PG) {
    int b = blockIdx.z;
    int m0 = blockIdx.y * 64, n0 = blockIdx.x * 64;
    __shared__ __align__(16) float Ws[16][68];  // [k][row]
    __shared__ __align__(16) float Xs[16][68];  // [k][col]
    int t = threadIdx.x;
    int tx = t & 15, ty = t >> 4;
    float acc[4][4] = {};
    const float* xb = x + (long)b * kC * kN;
    const float* wbase = (m0 < kCI) ? (phi_w + (long)m0 * kC)
                                    : (g_w + (long)(m0 - kCI) * kC);
    for (int kc = 0; kc < kC; kc += 16) {
        __syncthreads();
        {   // W tile: 64 rows x 16 cols
            int r = t >> 2, c4 = (t & 3) * 4;
            float4 v = *(const float4*)(wbase + (long)r * kC + kc + c4);
            Ws[c4 + 0][r] = v.x; Ws[c4 + 1][r] = v.y;
            Ws[c4 + 2][r] = v.z; Ws[c4 + 3][r] = v.w;
        }
        {   // X tile: 16 rows(k) x 64 cols
            int k = t >> 4, c4 = (t & 15) * 4;
            *(float4*)&Xs[k][c4] = *(const float4*)(xb + (long)(kc + k) * kN + n0 + c4);
        }
        __syncthreads();
#pragma unroll
        for (int k = 0; k < 16; k++) {
            float4 a = *(const float4*)&Ws[k][4 * ty];
            float4 bv = *(const float4*)&Xs[k][4 * tx];
            float av[4] = {a.x, a.y, a.z, a.w};
            float bw[4] = {bv.x, bv.y, bv.z, bv.w};
#pragma unroll
            for (int i = 0; i < 4; i++)
#pragma unroll
                for (int j = 0; j < 4; j++) acc[i][j] += av[i] * bw[j];
        }
    }
    float* pb = PG + (long)b * kC * kN;
#pragma unroll
    for (int i = 0; i < 4; i++) {
        int row = m0 + ty * 4 + i;
        float4 ov = {acc[i][0], acc[i][1], acc[i][2], acc[i][3]};
        *(float4*)(pb + (long)row * kN + n0 + tx * 4) = ov;
    }
}

// ---- rs[b][r] = sum over n of PG[b][r][n] ---------------------------------
__global__ void rowsum_kernel(const float* __restrict__ PG, float* __restrict__ rs) {
    int br = blockIdx.x;  // 0 .. kB*kC-1
    const float* p = PG + (long)br * kN;
    float s = 0.f;
    for (int i = threadIdx.x * 4; i < kN; i += 1024) {
        float4 v = *(const float4*)(p + i);
        s += v.x + v.y + v.z + v.w;
    }
    __shared__ float sm[256];
    sm[threadIdx.x] = s;
    __syncthreads();
    for (int st = 128; st > 0; st >>= 1) {
        if (threadIdx.x < st) sm[threadIdx.x] += sm[threadIdx.x + st];
        __syncthreads();
    }
    if (threadIdx.x == 0) rs[br] = sm[0];
}

// ---- Tpart[b][s] quadrant = Phi[rows, slice] * G2[rows, slice]^T ----------
// blockIdx.y selects the 64x64 quadrant of the 128x128 tile.
__global__ void __launch_bounds__(256, 4)
tsplit_kernel(const float* __restrict__ PG, float* __restrict__ Tpart) {
    int s = blockIdx.x, b = blockIdx.z;
    int qy = blockIdx.y >> 1, qx = blockIdx.y & 1;
    int mbase = s * (kN / kSplits);  // 64 m's per slice
    __shared__ __align__(16) float As[16][68];  // [m][c]   (Phi rows)
    __shared__ __align__(16) float Bs[16][68];  // [m][c']  (G2 rows)
    int t = threadIdx.x;
    int tx = t & 15, ty = t >> 4;
    float acc[4][4] = {};
    const float* Phi = PG + (long)b * kC * kN + (long)(64 * qy) * kN;
    const float* G2  = PG + (long)b * kC * kN + (long)(kCI + 64 * qx) * kN;
    for (int mc = 0; mc < kN / kSplits; mc += 16) {
        __syncthreads();
        {   // each operand: 64 rows x 16 m
            int r = t >> 2, c4 = (t & 3) * 4;
            float4 va = *(const float4*)(Phi + (long)r * kN + mbase + mc + c4);
            As[c4 + 0][r] = va.x; As[c4 + 1][r] = va.y;
            As[c4 + 2][r] = va.z; As[c4 + 3][r] = va.w;
            float4 vb = *(const float4*)(G2 + (long)r * kN + mbase + mc + c4);
            Bs[c4 + 0][r] = vb.x; Bs[c4 + 1][r] = vb.y;
            Bs[c4 + 2][r] = vb.z; Bs[c4 + 3][r] = vb.w;
        }
        __syncthreads();
#pragma unroll
        for (int k = 0; k < 16; k++) {
            float4 a = *(const float4*)&As[k][4 * ty];
            float4 bv = *(const float4*)&Bs[k][4 * tx];
            float av[4] = {a.x, a.y, a.z, a.w};
            float bw[4] = {bv.x, bv.y, bv.z, bv.w};
#pragma unroll
            for (int i = 0; i < 4; i++)
#pragma unroll
                for (int j = 0; j < 4; j++) acc[i][j] += av[i] * bw[j];
        }
    }
    float* Tp = Tpart + ((long)b * kSplits + s) * kCI * kCI;
#pragma unroll
    for (int i = 0; i < 4; i++) {
        int c = 64 * qy + ty * 4 + i;
        float4 ov = {acc[i][0], acc[i][1], acc[i][2], acc[i][3]};
        *(float4*)(Tp + (long)c * kCI + 64 * qx + tx * 4) = ov;
    }
}

// ---- T[b] = sum_s Tpart[b][s] - rsPhi*rsG2^T/N ----------------------------
__global__ void treduce_kernel(const float* __restrict__ Tpart, const float* __restrict__ rs,
                               float* __restrict__ T) {
    int idx = blockIdx.x * 256 + threadIdx.x;  // 0 .. kB*kCI*kCI-1
    int b = idx >> 14;
    int c = (idx >> 7) & 127, cp = idx & 127;
    const float* tp = Tpart + (long)b * kSplits * kCI * kCI + (idx & 16383);
    float s = 0.f;
#pragma unroll 8
    for (int sl = 0; sl < kSplits; sl++) s += tp[(long)sl * kCI * kCI];
    s -= rs[b * kC + c] * rs[b * kC + kCI + cp] * (1.f / kN);
    T[idx] = s;
}

// ---- NT gemm, 64x64 tile, 4x4/thread: C[b][m][n] = sum_k A[b][m][k]*B[b][n][k]
__global__ void __launch_bounds__(256, 4)
nt64_gemm(const float* __restrict__ A, const float* __restrict__ B,
          float* __restrict__ Cm, int M, int N, int K,
          long sA, long sB, long sC) {
    int b = blockIdx.z;
    const float* Ab = A + (long)b * sA;
    const float* Bb = B + (long)b * sB;
    float* Cb = Cm + (long)b * sC;
    __shared__ __align__(16) float As[16][68];  // [k][row]
    __shared__ __align__(16) float Bs[16][68];
    int t = threadIdx.x;
    int tx = t & 15, ty = t >> 4;
    int m0 = blockIdx.y * 64, n0 = blockIdx.x * 64;
    float acc[4][4] = {};
    for (int kc = 0; kc < K; kc += 16) {
        __syncthreads();
        {
            int r = t >> 2, c4 = (t & 3) * 4;
            float4 va = *(const float4*)(Ab + (long)(m0 + r) * K + kc + c4);
            As[c4 + 0][r] = va.x; As[c4 + 1][r] = va.y;
            As[c4 + 2][r] = va.z; As[c4 + 3][r] = va.w;
            float4 vb = *(const float4*)(Bb + (long)(n0 + r) * K + kc + c4);
            Bs[c4 + 0][r] = vb.x; Bs[c4 + 1][r] = vb.y;
            Bs[c4 + 2][r] = vb.z; Bs[c4 + 3][r] = vb.w;
        }
        __syncthreads();
#pragma unroll
        for (int k = 0; k < 16; k++) {
            float4 a = *(const float4*)&As[k][4 * ty];
            float4 bv = *(const float4*)&Bs[k][4 * tx];
            float av[4] = {a.x, a.y, a.z, a.w};
            float bw[4] = {bv.x, bv.y, bv.z, bv.w};
#pragma unroll
            for (int i = 0; i < 4; i++)
#pragma unroll
                for (int j = 0; j < 4; j++) acc[i][j] += av[i] * bw[j];
        }
    }
#pragma unroll
    for (int i = 0; i < 4; i++) {
        float4 ov = {acc[i][0], acc[i][1], acc[i][2], acc[i][3]};
        *(float4*)(Cb + (long)(m0 + 4 * ty + i) * N + n0 + 4 * tx) = ov;
    }
}

// ---- beta[b,o] = out_b[o] + sum_k theta_bc[k] * W2t[b,o,k] ----------------
__global__ void beta_kernel(const float* __restrict__ W2t, const float* __restrict__ tbc,
                            const float* __restrict__ out_b, float* __restrict__ beta) {
    int i = blockIdx.x * blockDim.x + threadIdx.x;  // b*kC + o
    if (i >= kB * kC) return;
    int o = i & (kC - 1);
    float s = out_b[o];
    const float* row = W2t + (long)i * kCI;
#pragma unroll 8
    for (int k = 0; k < kCI; k++) s += tbc[k] * row[k];
    beta[i] = s;
}

// ---- out[b,o,n] = x[b,o,n] + sum_c Mt[b,o,c]*x[b,c,n] + beta[b,o] ---------
// 64(o) x 64(n) tile, 256 threads, 4x4 per thread, K=kC in chunks of 16.
__global__ void __launch_bounds__(256, 4)
final_kernel(const float* __restrict__ x, const float* __restrict__ Mt,
             const float* __restrict__ beta, float* __restrict__ out) {
    int b = blockIdx.z;
    int o0 = blockIdx.y * 64, n0 = blockIdx.x * 64;
    __shared__ __align__(16) float Ms[16][68];  // [k][o-row]
    __shared__ __align__(16) float Xs[16][68];  // [k][n-col]
    int t = threadIdx.x;
    int tx = t & 15, ty = t >> 4;
    float acc[4][4] = {};
    const float* xb = x + (long)b * kC * kN;
    const float* Mb = Mt + (long)b * kC * kC;
    for (int kc = 0; kc < kC; kc += 16) {
        __syncthreads();
        {   // Mt tile: 64 rows x 16 cols
            int r = t >> 2, c4 = (t & 3) * 4;
            float4 v = *(const float4*)(Mb + (long)(o0 + r) * kC + kc + c4);
            Ms[c4 + 0][r] = v.x; Ms[c4 + 1][r] = v.y;
            Ms[c4 + 2][r] = v.z; Ms[c4 + 3][r] = v.w;
        }
        {   // X tile: 16 rows(ch) x 64 cols
            int k = t >> 4, c4 = (t & 15) * 4;
            *(float4*)&Xs[k][c4] = *(const float4*)(xb + (long)(kc + k) * kN + n0 + c4);
        }
        __syncthreads();
#pragma unroll
        for (int k = 0; k < 16; k++) {
            float4 a = *(const float4*)&Ms[k][4 * ty];
            float4 bv = *(const float4*)&Xs[k][4 * tx];
            float av[4] = {a.x, a.y, a.z, a.w};
            float bw[4] = {bv.x, bv.y, bv.z, bv.w};
#pragma unroll
            for (int i = 0; i < 4; i++)
#pragma unroll
                for (int j = 0; j < 4; j++) acc[i][j] += av[i] * bw[j];
        }
    }
#pragma unroll
    for (int i = 0; i < 4; i++) {
        int o = o0 + ty * 4 + i;
        float bt = beta[b * kC + o];
        long base = (long)b * kC * kN + (long)o * kN + n0 + tx * 4;
        float4 xv = *(const float4*)(x + base);
        float4 ov = {acc[i][0] + xv.x + bt, acc[i][1] + xv.y + bt,
                     acc[i][2] + xv.z + bt, acc[i][3] + xv.w + bt};
        *(float4*)(out + base) = ov;
    }
}

extern "C" void kernel_launch(void* const* d_in, const int* in_sizes, int n_in,
                              void* d_out, int out_size, void* d_ws, size_t ws_size,
                              hipStream_t stream) {
    const float* x       = (const float*)d_in[0];
    const float* g_w     = (const float*)d_in[1];
    // d_in[2] = g_b   : cancelled (rows of Phic sum to 0)
    const float* theta_w = (const float*)d_in[3];
    const float* theta_b = (const float*)d_in[4];
    const float* phi_w   = (const float*)d_in[5];
    // d_in[6] = phi_b : cancelled by spatial centering
    const float* out_w   = (const float*)d_in[7];
    const float* out_b   = (const float*)d_in[8];
    float* out = (float*)d_out;
    float* ws  = (float*)d_ws;  // needs ~35.5 MB

    float* twcT  = ws + kOffTwcT;
    float* tbc   = ws + kOffTbc;
    float* PG    = ws + kOffPG;
    float* rs    = ws + kOffRs;
    float* Tpart = ws + kOffTpart;
    float* T     = ws + kOffT;
    float* W2t   = ws + kOffW2t;
    float* Mt    = ws + kOffMt;
    float* beta  = ws + kOffBeta;

    centerw_kernel<<<1, 256, 0, stream>>>(theta_w, theta_b, twcT, tbc);
    // PG[b] = [phi_w; g_w] * X[b]   (256 x 4096, K=256)
    pg_gemm<<<dim3(kN / 64, 4, kB), 256, 0, stream>>>(phi_w, g_w, x, PG);
    rowsum_kernel<<<kB * kC, 256, 0, stream>>>(PG, rs);
    // Tpart[b][s] = Phi_slice * G2_slice^T  (quadrant per block)
    tsplit_kernel<<<dim3(kSplits, 4, kB), 256, 0, stream>>>(PG, Tpart);
    // T[b] = sum_s Tpart - rs outer correction
    treduce_kernel<<<kB * kCI * kCI / 256, 256, 0, stream>>>(Tpart, rs, T);
    // W2t[b] = out_w * T[b]^T       (M=256, N=128, K=128)
    nt64_gemm<<<dim3(2, 4, kB), 256, 0, stream>>>(out_w, T, W2t, kC, kCI, kCI,
                                                  0, (long)kCI * kCI, (long)kC * kCI);
    // Mt[b] = W2t[b] * theta_wc     (M=256, N=256, K=128)
    nt64_gemm<<<dim3(4, 4, kB), 256, 0, stream>>>(W2t, twcT, Mt, kC, kC, kCI,
                                                  (long)kC * kCI, 0, (long)kC * kC);
    beta_kernel<<<kB, 256, 0, stream>>>(W2t, tbc, out_b, beta);
    final_kernel<<<dim3(kN / 64, 4, kB), 256, 0, stream>>>(x, Mt, beta, out);
}

// Round 5
// 159.770 us; speedup vs baseline: 2.3050x; 1.2330x over previous
//
#include <hip/hip_runtime.h>

// Problem constants (B, C, CI, H, W) = (4, 256, 128, 64, 64)
constexpr int kB  = 4;
constexpr int kC  = 256;
constexpr int kCI = 128;
constexpr int kN  = 64 * 64;  // 4096

// ---------------------------------------------------------------------------
// Algebraic collapse (no gram, no pairwise):
//   Phi = phi_w*X, G2 = g_w*X                (CI x N each; stacked as PG)
//   T   = Phic*G2^T = Phi*G2^T - rsPhi*rsG2^T/N     (CI x CI per batch)
//   W2t = out_w * T^T ; Mt = W2t * theta_wc ; beta = W2t*theta_bc + out_b
//   out[b,o,n] = x[b,o,n] + sum_c Mt[b,o,c]*x[b,c,n] + beta[b,o]
//
// ROUND-5: pg and final move to bf16 MFMA (v_mfma_f32_16x16x32_bf16, fp32
// accum). xT = bf16 transpose of x gives the B-operand in natural [n][k]
// fragment layout. tsplit/treduce/nt64 stay fp32 (error margin). Round-4
// lesson kept: small per-thread acc (8 f32x4 = 32 VGPR), launch_bounds.
// ---------------------------------------------------------------------------

constexpr int kSplits = 64;

typedef __attribute__((ext_vector_type(8))) short bf16x8;   // 8 bf16 = 4 VGPR
typedef __attribute__((ext_vector_type(4))) float f32x4;

__device__ inline ushort f2b(float f) {  // fp32 -> bf16, round-nearest-even
    unsigned u = __float_as_uint(f);
    return (ushort)((u + 0x7FFF + ((u >> 16) & 1)) >> 16);
}

// ws layout (float units)
constexpr long kOffTwcT  = 0;                            // 32768
constexpr long kOffTbc   = kOffTwcT + kC * kCI;          // 128
constexpr long kOffPG    = kOffTbc + kCI;                // 4194304 (fp32)
constexpr long kOffRs    = kOffPG + (long)kB * kC * kN;  // 1024
constexpr long kOffTpart = kOffRs + kB * kC;             // 4194304
constexpr long kOffT     = kOffTpart + (long)kB * kSplits * kCI * kCI;
constexpr long kOffW2t   = kOffT + kB * kCI * kCI;
constexpr long kOffMt    = kOffW2t + kB * kC * kCI;
constexpr long kOffBeta  = kOffMt + kB * kC * kC;
constexpr long kOffXT    = kOffBeta + kB * kC;           // bf16 region: kB*kN*kC ushorts
// total ~ 44.8 MB of d_ws

// ---- xT[b][n][c] (bf16) = x[b][c][n] --------------------------------------
__global__ void __launch_bounds__(256, 4)
xt_kernel(const float* __restrict__ x, ushort* __restrict__ xT) {
    int b = blockIdx.z;
    int n0 = blockIdx.x * 64, c0 = blockIdx.y * 64;
    __shared__ float ft[64][66];
    int t = threadIdx.x;
    const float* xb = x + (long)b * kC * kN;
#pragma unroll
    for (int i = 0; i < 4; i++) {
        int l = t + 256 * i;
        int row = l >> 4, col4 = (l & 15) * 4;  // row = c index, col = n
        float4 v = *(const float4*)(xb + (long)(c0 + row) * kN + n0 + col4);
        ft[row][col4 + 0] = v.x; ft[row][col4 + 1] = v.y;
        ft[row][col4 + 2] = v.z; ft[row][col4 + 3] = v.w;
    }
    __syncthreads();
    {   // write: thread t -> n-row (t>>2), 16-c segment ((t&3)*16)
        int n = t >> 2, cs = (t & 3) * 16;
        unsigned w[8];
#pragma unroll
        for (int j = 0; j < 8; j++) {
            ushort lo = f2b(ft[cs + 2 * j][n]);
            ushort hi = f2b(ft[cs + 2 * j + 1][n]);
            w[j] = (unsigned)lo | ((unsigned)hi << 16);
        }
        ushort* dst = xT + ((long)b * kN + n0 + n) * kC + c0 + cs;
        ((uint4*)dst)[0] = make_uint4(w[0], w[1], w[2], w[3]);
        ((uint4*)dst)[1] = make_uint4(w[4], w[5], w[6], w[7]);
    }
}

// ---- theta_w column-centered (transposed) + theta_b centered --------------
__global__ void centerw_kernel(const float* __restrict__ theta_w,
                               const float* __restrict__ theta_b,
                               float* __restrict__ twcT, float* __restrict__ tbc) {
    __shared__ float sm[128];
    int t = threadIdx.x;
    if (t < 128) sm[t] = theta_b[t];
    __syncthreads();
    for (int st = 64; st > 0; st >>= 1) {
        if (t < st) sm[t] += sm[t + st];
        __syncthreads();
    }
    float bmean = sm[0] * (1.f / kCI);
    float m = 0.f;
    for (int k = 0; k < kCI; k++) m += theta_w[k * kC + t];
    m *= (1.f / kCI);
    for (int k = 0; k < kCI; k++) twcT[t * kCI + k] = theta_w[k * kC + t] - m;
    if (t < 128) tbc[t] = theta_b[t] - bmean;
}

// ---- PG[b][r][n] (fp32) = [phi_w; g_w](bf16) x xT(bf16)  via MFMA ---------
// Block: 128(r) x 64(n); 4 waves, each 32(r) x 64(n) = 2x4 MFMA tiles.
// blockIdx.y: 0 -> phi_w rows, 1 -> g_w rows (aligned with the 128 split).
__global__ void __launch_bounds__(256, 2)
pg_mfma(const float* __restrict__ phi_w, const float* __restrict__ g_w,
        const ushort* __restrict__ xT, float* __restrict__ PG) {
    int b = blockIdx.z;
    int r0 = blockIdx.y * 128, n0 = blockIdx.x * 64;
    const float* wbase = blockIdx.y == 0 ? phi_w : g_w;
    __shared__ ushort Ws[128 * 40];  // [row][k] bf16, row stride 40 (80 B)
    __shared__ ushort Xs[64 * 40];
    int t = threadIdx.x;
    int w = t >> 6, lane = t & 63, q = lane >> 4, ln = lane & 15;
    f32x4 acc[2][4];
#pragma unroll
    for (int i = 0; i < 2; i++)
#pragma unroll
        for (int j = 0; j < 4; j++) acc[i][j] = 0.f;
    const ushort* xTb = xT + ((long)b * kN + n0) * kC;
    for (int kc = 0; kc < kC; kc += 32) {
        __syncthreads();
        // stage W: 128 rows x 32 k (fp32 -> bf16)
#pragma unroll
        for (int it = 0; it < 4; it++) {
            int l = t + 256 * it;
            int row = l >> 3, seg = l & 7;  // 8 segs of 4 floats
            float4 v = *(const float4*)(wbase + (long)row * kC + kc + seg * 4);
            ushort4 u = {f2b(v.x), f2b(v.y), f2b(v.z), f2b(v.w)};
            *(ushort4*)&Ws[row * 40 + seg * 4] = u;
        }
        // stage X: 64 rows x 32 k (bf16 copy)
        {
            int row = t >> 2, seg = t & 3;  // 4 segs of 8 bf16
            uint4 v = *(const uint4*)(xTb + (long)row * kC + kc + seg * 8);
            *(uint4*)&Xs[row * 40 + seg * 8] = v;
        }
        __syncthreads();
        bf16x8 a[2], bb[4];
#pragma unroll
        for (int mt = 0; mt < 2; mt++)
            a[mt] = *(const bf16x8*)&Ws[(32 * w + 16 * mt + ln) * 40 + q * 8];
#pragma unroll
        for (int nt = 0; nt < 4; nt++)
            bb[nt] = *(const bf16x8*)&Xs[(16 * nt + ln) * 40 + q * 8];
#pragma unroll
        for (int mt = 0; mt < 2; mt++)
#pragma unroll
            for (int nt = 0; nt < 4; nt++)
                acc[mt][nt] = __builtin_amdgcn_mfma_f32_16x16x32_bf16(
                    a[mt], bb[nt], acc[mt][nt], 0, 0, 0);
    }
    // D layout: col = lane&15, row = quad*4 + reg  [m89-verified]
    float* pb = PG + (long)b * kC * kN;
#pragma unroll
    for (int mt = 0; mt < 2; mt++)
#pragma unroll
        for (int nt = 0; nt < 4; nt++)
#pragma unroll
            for (int i = 0; i < 4; i++) {
                int row = r0 + 32 * w + 16 * mt + 4 * q + i;
                int col = n0 + 16 * nt + ln;
                pb[(long)row * kN + col] = acc[mt][nt][i];
            }
}

// ---- rs[b][r] = sum over n of PG[b][r][n] ---------------------------------
__global__ void rowsum_kernel(const float* __restrict__ PG, float* __restrict__ rs) {
    int br = blockIdx.x;
    const float* p = PG + (long)br * kN;
    float s = 0.f;
    for (int i = threadIdx.x * 4; i < kN; i += 1024) {
        float4 v = *(const float4*)(p + i);
        s += v.x + v.y + v.z + v.w;
    }
    __shared__ float sm[256];
    sm[threadIdx.x] = s;
    __syncthreads();
    for (int st = 128; st > 0; st >>= 1) {
        if (threadIdx.x < st) sm[threadIdx.x] += sm[threadIdx.x + st];
        __syncthreads();
    }
    if (threadIdx.x == 0) rs[br] = sm[0];
}

// ---- Tpart[b][s] quadrant = Phi[rows, slice] * G2[rows, slice]^T (fp32) ---
__global__ void __launch_bounds__(256, 4)
tsplit_kernel(const float* __restrict__ PG, float* __restrict__ Tpart) {
    int s = blockIdx.x, b = blockIdx.z;
    int qy = blockIdx.y >> 1, qx = blockIdx.y & 1;
    int mbase = s * (kN / kSplits);
    __shared__ __align__(16) float As[16][68];
    __shared__ __align__(16) float Bs[16][68];
    int t = threadIdx.x;
    int tx = t & 15, ty = t >> 4;
    float acc[4][4] = {};
    const float* Phi = PG + (long)b * kC * kN + (long)(64 * qy) * kN;
    const float* G2  = PG + (long)b * kC * kN + (long)(kCI + 64 * qx) * kN;
    for (int mc = 0; mc < kN / kSplits; mc += 16) {
        __syncthreads();
        {
            int r = t >> 2, c4 = (t & 3) * 4;
            float4 va = *(const float4*)(Phi + (long)r * kN + mbase + mc + c4);
            As[c4 + 0][r] = va.x; As[c4 + 1][r] = va.y;
            As[c4 + 2][r] = va.z; As[c4 + 3][r] = va.w;
            float4 vb = *(const float4*)(G2 + (long)r * kN + mbase + mc + c4);
            Bs[c4 + 0][r] = vb.x; Bs[c4 + 1][r] = vb.y;
            Bs[c4 + 2][r] = vb.z; Bs[c4 + 3][r] = vb.w;
        }
        __syncthreads();
#pragma unroll
        for (int k = 0; k < 16; k++) {
            float4 a = *(const float4*)&As[k][4 * ty];
            float4 bv = *(const float4*)&Bs[k][4 * tx];
            float av[4] = {a.x, a.y, a.z, a.w};
            float bw[4] = {bv.x, bv.y, bv.z, bv.w};
#pragma unroll
            for (int i = 0; i < 4; i++)
#pragma unroll
                for (int j = 0; j < 4; j++) acc[i][j] += av[i] * bw[j];
        }
    }
    float* Tp = Tpart + ((long)b * kSplits + s) * kCI * kCI;
#pragma unroll
    for (int i = 0; i < 4; i++) {
        int c = 64 * qy + ty * 4 + i;
        float4 ov = {acc[i][0], acc[i][1], acc[i][2], acc[i][3]};
        *(float4*)(Tp + (long)c * kCI + 64 * qx + tx * 4) = ov;
    }
}

// ---- T[b] = sum_s Tpart[b][s] - rsPhi*rsG2^T/N ----------------------------
__global__ void treduce_kernel(const float* __restrict__ Tpart, const float* __restrict__ rs,
                               float* __restrict__ T) {
    int idx = blockIdx.x * 256 + threadIdx.x;
    int b = idx >> 14;
    int c = (idx >> 7) & 127, cp = idx & 127;
    const float* tp = Tpart + (long)b * kSplits * kCI * kCI + (idx & 16383);
    float s = 0.f;
#pragma unroll 8
    for (int sl = 0; sl < kSplits; sl++) s += tp[(long)sl * kCI * kCI];
    s -= rs[b * kC + c] * rs[b * kC + kCI + cp] * (1.f / kN);
    T[idx] = s;
}

// ---- NT gemm, 64x64 tile, 4x4/thread --------------------------------------
__global__ void __launch_bounds__(256, 4)
nt64_gemm(const float* __restrict__ A, const float* __restrict__ B,
          float* __restrict__ Cm, int M, int N, int K,
          long sA, long sB, long sC) {
    int b = blockIdx.z;
    const float* Ab = A + (long)b * sA;
    const float* Bb = B + (long)b * sB;
    float* Cb = Cm + (long)b * sC;
    __shared__ __align__(16) float As[16][68];
    __shared__ __align__(16) float Bs[16][68];
    int t = threadIdx.x;
    int tx = t & 15, ty = t >> 4;
    int m0 = blockIdx.y * 64, n0 = blockIdx.x * 64;
    float acc[4][4] = {};
    for (int kc = 0; kc < K; kc += 16) {
        __syncthreads();
        {
            int r = t >> 2, c4 = (t & 3) * 4;
            float4 va = *(const float4*)(Ab + (long)(m0 + r) * K + kc + c4);
            As[c4 + 0][r] = va.x; As[c4 + 1][r] = va.y;
            As[c4 + 2][r] = va.z; As[c4 + 3][r] = va.w;
            float4 vb = *(const float4*)(Bb + (long)(n0 + r) * K + kc + c4);
            Bs[c4 + 0][r] = vb.x; Bs[c4 + 1][r] = vb.y;
            Bs[c4 + 2][r] = vb.z; Bs[c4 + 3][r] = vb.w;
        }
        __syncthreads();
#pragma unroll
        for (int k = 0; k < 16; k++) {
            float4 a = *(const float4*)&As[k][4 * ty];
            float4 bv = *(const float4*)&Bs[k][4 * tx];
            float av[4] = {a.x, a.y, a.z, a.w};
            float bw[4] = {bv.x, bv.y, bv.z, bv.w};
#pragma unroll
            for (int i = 0; i < 4; i++)
#pragma unroll
                for (int j = 0; j < 4; j++) acc[i][j] += av[i] * bw[j];
        }
    }
#pragma unroll
    for (int i = 0; i < 4; i++) {
        float4 ov = {acc[i][0], acc[i][1], acc[i][2], acc[i][3]};
        *(float4*)(Cb + (long)(m0 + 4 * ty + i) * N + n0 + 4 * tx) = ov;
    }
}

// ---- beta[b,o] = out_b[o] + sum_k theta_bc[k] * W2t[b,o,k] ----------------
__global__ void beta_kernel(const float* __restrict__ W2t, const float* __restrict__ tbc,
                            const float* __restrict__ out_b, float* __restrict__ beta) {
    int i = blockIdx.x * blockDim.x + threadIdx.x;
    if (i >= kB * kC) return;
    int o = i & (kC - 1);
    float s = out_b[o];
    const float* row = W2t + (long)i * kCI;
#pragma unroll 8
    for (int k = 0; k < kCI; k++) s += tbc[k] * row[k];
    beta[i] = s;
}

// ---- out = x + Mt(bf16) x xT(bf16) + beta  via MFMA -----------------------
// Same engine as pg_mfma; A = Mt rows (cvt in staging), epilogue adds x+beta.
__global__ void __launch_bounds__(256, 2)
final_mfma(const float* __restrict__ x, const float* __restrict__ Mt,
           const ushort* __restrict__ xT, const float* __restrict__ beta,
           float* __restrict__ out) {
    int b = blockIdx.z;
    int o0 = blockIdx.y * 128, n0 = blockIdx.x * 64;
    const float* Mb = Mt + (long)b * kC * kC;
    __shared__ ushort Ws[128 * 40];
    __shared__ ushort Xs[64 * 40];
    int t = threadIdx.x;
    int w = t >> 6, lane = t & 63, q = lane >> 4, ln = lane & 15;
    f32x4 acc[2][4];
#pragma unroll
    for (int i = 0; i < 2; i++)
#pragma unroll
        for (int j = 0; j < 4; j++) acc[i][j] = 0.f;
    const ushort* xTb = xT + ((long)b * kN + n0) * kC;
    for (int kc = 0; kc < kC; kc += 32) {
        __syncthreads();
#pragma unroll
        for (int it = 0; it < 4; it++) {
            int l = t + 256 * it;
            int row = l >> 3, seg = l & 7;
            float4 v = *(const float4*)(Mb + (long)(o0 + row) * kC + kc + seg * 4);
            ushort4 u = {f2b(v.x), f2b(v.y), f2b(v.z), f2b(v.w)};
            *(ushort4*)&Ws[row * 40 + seg * 4] = u;
        }
        {
            int row = t >> 2, seg = t & 3;
            uint4 v = *(const uint4*)(xTb + (long)row * kC + kc + seg * 8);
            *(uint4*)&Xs[row * 40 + seg * 8] = v;
        }
        __syncthreads();
        bf16x8 a[2], bb[4];
#pragma unroll
        for (int mt = 0; mt < 2; mt++)
            a[mt] = *(const bf16x8*)&Ws[(32 * w + 16 * mt + ln) * 40 + q * 8];
#pragma unroll
        for (int nt = 0; nt < 4; nt++)
            bb[nt] = *(const bf16x8*)&Xs[(16 * nt + ln) * 40 + q * 8];
#pragma unroll
        for (int mt = 0; mt < 2; mt++)
#pragma unroll
            for (int nt = 0; nt < 4; nt++)
                acc[mt][nt] = __builtin_amdgcn_mfma_f32_16x16x32_bf16(
                    a[mt], bb[nt], acc[mt][nt], 0, 0, 0);
    }
    const float* xb = x + (long)b * kC * kN;
    float* ob = out + (long)b * kC * kN;
#pragma unroll
    for (int mt = 0; mt < 2; mt++)
#pragma unroll
        for (int nt = 0; nt < 4; nt++)
#pragma unroll
            for (int i = 0; i < 4; i++) {
                int row = o0 + 32 * w + 16 * mt + 4 * q + i;
                int col = n0 + 16 * nt + ln;
                long idx = (long)row * kN + col;
                ob[idx] = acc[mt][nt][i] + xb[idx] + beta[b * kC + row];
            }
}

extern "C" void kernel_launch(void* const* d_in, const int* in_sizes, int n_in,
                              void* d_out, int out_size, void* d_ws, size_t ws_size,
                              hipStream_t stream) {
    const float* x       = (const float*)d_in[0];
    const float* g_w     = (const float*)d_in[1];
    // d_in[2] = g_b   : cancelled (rows of Phic sum to 0)
    const float* theta_w = (const float*)d_in[3];
    const float* theta_b = (const float*)d_in[4];
    const float* phi_w   = (const float*)d_in[5];
    // d_in[6] = phi_b : cancelled by spatial centering
    const float* out_w   = (const float*)d_in[7];
    const float* out_b   = (const float*)d_in[8];
    float* out = (float*)d_out;
    float* ws  = (float*)d_ws;  // needs ~45 MB

    float*  twcT  = ws + kOffTwcT;
    float*  tbc   = ws + kOffTbc;
    float*  PG    = ws + kOffPG;
    float*  rs    = ws + kOffRs;
    float*  Tpart = ws + kOffTpart;
    float*  T     = ws + kOffT;
    float*  W2t   = ws + kOffW2t;
    float*  Mt    = ws + kOffMt;
    float*  beta  = ws + kOffBeta;
    ushort* xT    = (ushort*)(ws + kOffXT);

    // xT[b][n][c] = bf16(x[b][c][n])
    xt_kernel<<<dim3(kN / 64, kC / 64, kB), 256, 0, stream>>>(x, xT);
    centerw_kernel<<<1, 256, 0, stream>>>(theta_w, theta_b, twcT, tbc);
    // PG[b] = [phi_w; g_w] * X[b]   (MFMA bf16, fp32 out)
    pg_mfma<<<dim3(kN / 64, 2, kB), 256, 0, stream>>>(phi_w, g_w, xT, PG);
    rowsum_kernel<<<kB * kC, 256, 0, stream>>>(PG, rs);
    // Tpart[b][s] = Phi_slice * G2_slice^T  (fp32, quadrant per block)
    tsplit_kernel<<<dim3(kSplits, 4, kB), 256, 0, stream>>>(PG, Tpart);
    treduce_kernel<<<kB * kCI * kCI / 256, 256, 0, stream>>>(Tpart, rs, T);
    // W2t[b] = out_w * T[b]^T       (M=256, N=128, K=128)
    nt64_gemm<<<dim3(2, 4, kB), 256, 0, stream>>>(out_w, T, W2t, kC, kCI, kCI,
                                                  0, (long)kCI * kCI, (long)kC * kCI);
    // Mt[b] = W2t[b] * theta_wc     (M=256, N=256, K=128)
    nt64_gemm<<<dim3(4, 4, kB), 256, 0, stream>>>(W2t, twcT, Mt, kC, kC, kCI,
                                                  (long)kC * kCI, 0, (long)kC * kC);
    beta_kernel<<<kB, 256, 0, stream>>>(W2t, tbc, out_b, beta);
    // out = x + Mt * X + beta       (MFMA bf16 + fp32 residual epilogue)
    final_mfma<<<dim3(kN / 64, 2, kB), 256, 0, stream>>>(x, Mt, xT, beta, out);
}

// Round 6
// 150.977 us; speedup vs baseline: 2.4393x; 1.0582x over previous
//
#include <hip/hip_runtime.h>

// Problem constants (B, C, CI, H, W) = (4, 256, 128, 64, 64)
constexpr int kB  = 4;
constexpr int kC  = 256;
constexpr int kCI = 128;
constexpr int kN  = 64 * 64;  // 4096

// ---------------------------------------------------------------------------
// Algebraic collapse (no gram, no pairwise):
//   Phi = phi_w*X, G2 = g_w*X                (CI x N each; stacked as PG)
//   T   = Phic*G2^T = Phi*G2^T - rsPhi*rsG2^T/N     (CI x CI per batch)
//   W2t = out_w * T^T ; Mt = W2t * theta_wc ; beta = W2t*theta_bc + out_b
//   out[b,o,n] = x[b,o,n] + sum_c Mt[b,o,c]*x[b,c,n] + beta[b,o]
//
// ROUND-6: PG stored bf16; tsplit becomes an MFMA NT gemm (PG rows are
// [channel][spatial] k-contiguous = natural fragment layout). kSplits 64->16,
// Tpart 16.8->4.2 MB. rs computed from the SAME quantized bf16 PG that feeds
// T, so the centering correction cancels exactly in the quantized algebra.
// Fixed harness floor ~112 us (268 MB ws re-poison fills); own kernels ~28 us.
// ---------------------------------------------------------------------------

constexpr int kSplits = 16;
constexpr int kSliceN = kN / kSplits;  // 256

typedef __attribute__((ext_vector_type(8))) short bf16x8;   // 8 bf16 = 4 VGPR
typedef __attribute__((ext_vector_type(4))) float f32x4;

__device__ inline ushort f2b(float f) {  // fp32 -> bf16, round-nearest-even
    unsigned u = __float_as_uint(f);
    return (ushort)((u + 0x7FFF + ((u >> 16) & 1)) >> 16);
}
__device__ inline float b2f(ushort u) { return __uint_as_float((unsigned)u << 16); }

// ws layout (float units)
constexpr long kOffTwcT  = 0;                                  // 32768
constexpr long kOffTbc   = kOffTwcT + kC * kCI;                // 128
constexpr long kOffPG    = kOffTbc + kCI;                      // bf16: kB*kC*kN ushorts = 2097152 floats
constexpr long kOffRs    = kOffPG + (long)kB * kC * kN / 2;    // 1024
constexpr long kOffTpart = kOffRs + kB * kC;                   // kB*kSplits*kCI*kCI = 1048576
constexpr long kOffT     = kOffTpart + (long)kB * kSplits * kCI * kCI;  // 65536
constexpr long kOffW2t   = kOffT + kB * kCI * kCI;             // 131072
constexpr long kOffMt    = kOffW2t + kB * kC * kCI;            // 262144
constexpr long kOffBeta  = kOffMt + kB * kC * kC;              // 1024
constexpr long kOffXT    = kOffBeta + kB * kC;                 // bf16: kB*kN*kC ushorts = 2097152 floats
// total ~5.74M floats = ~23 MB of d_ws

// ---- xT[b][n][c] (bf16) = x[b][c][n] --------------------------------------
__global__ void __launch_bounds__(256, 4)
xt_kernel(const float* __restrict__ x, ushort* __restrict__ xT) {
    int b = blockIdx.z;
    int n0 = blockIdx.x * 64, c0 = blockIdx.y * 64;
    __shared__ float ft[64][66];
    int t = threadIdx.x;
    const float* xb = x + (long)b * kC * kN;
#pragma unroll
    for (int i = 0; i < 4; i++) {
        int l = t + 256 * i;
        int row = l >> 4, col4 = (l & 15) * 4;  // row = c index, col = n
        float4 v = *(const float4*)(xb + (long)(c0 + row) * kN + n0 + col4);
        ft[row][col4 + 0] = v.x; ft[row][col4 + 1] = v.y;
        ft[row][col4 + 2] = v.z; ft[row][col4 + 3] = v.w;
    }
    __syncthreads();
    {   // write: thread t -> n-row (t>>2), 16-c segment ((t&3)*16)
        int n = t >> 2, cs = (t & 3) * 16;
        unsigned w[8];
#pragma unroll
        for (int j = 0; j < 8; j++) {
            ushort lo = f2b(ft[cs + 2 * j][n]);
            ushort hi = f2b(ft[cs + 2 * j + 1][n]);
            w[j] = (unsigned)lo | ((unsigned)hi << 16);
        }
        ushort* dst = xT + ((long)b * kN + n0 + n) * kC + c0 + cs;
        ((uint4*)dst)[0] = make_uint4(w[0], w[1], w[2], w[3]);
        ((uint4*)dst)[1] = make_uint4(w[4], w[5], w[6], w[7]);
    }
}

// ---- theta_w column-centered (transposed) + theta_b centered --------------
__global__ void centerw_kernel(const float* __restrict__ theta_w,
                               const float* __restrict__ theta_b,
                               float* __restrict__ twcT, float* __restrict__ tbc) {
    __shared__ float sm[128];
    int t = threadIdx.x;
    if (t < 128) sm[t] = theta_b[t];
    __syncthreads();
    for (int st = 64; st > 0; st >>= 1) {
        if (t < st) sm[t] += sm[t + st];
        __syncthreads();
    }
    float bmean = sm[0] * (1.f / kCI);
    float m = 0.f;
    for (int k = 0; k < kCI; k++) m += theta_w[k * kC + t];
    m *= (1.f / kCI);
    for (int k = 0; k < kCI; k++) twcT[t * kCI + k] = theta_w[k * kC + t] - m;
    if (t < 128) tbc[t] = theta_b[t] - bmean;
}

// ---- PG[b][r][n] (bf16) = [phi_w; g_w](bf16) x xT(bf16)  via MFMA ---------
// Block: 128(r) x 64(n); 4 waves, each 32(r) x 64(n) = 2x4 MFMA tiles.
// blockIdx.y: 0 -> phi_w rows, 1 -> g_w rows.
__global__ void __launch_bounds__(256, 2)
pg_mfma(const float* __restrict__ phi_w, const float* __restrict__ g_w,
        const ushort* __restrict__ xT, ushort* __restrict__ PGh) {
    int b = blockIdx.z;
    int r0 = blockIdx.y * 128, n0 = blockIdx.x * 64;
    const float* wbase = blockIdx.y == 0 ? phi_w : g_w;
    __shared__ ushort Ws[128 * 40];  // [row][k] bf16, row stride 40 (80 B)
    __shared__ ushort Xs[64 * 40];
    int t = threadIdx.x;
    int w = t >> 6, lane = t & 63, q = lane >> 4, ln = lane & 15;
    f32x4 acc[2][4];
#pragma unroll
    for (int i = 0; i < 2; i++)
#pragma unroll
        for (int j = 0; j < 4; j++) acc[i][j] = 0.f;
    const ushort* xTb = xT + ((long)b * kN + n0) * kC;
    for (int kc = 0; kc < kC; kc += 32) {
        __syncthreads();
        // stage W: 128 rows x 32 k (fp32 -> bf16)
#pragma unroll
        for (int it = 0; it < 4; it++) {
            int l = t + 256 * it;
            int row = l >> 3, seg = l & 7;  // 8 segs of 4 floats
            float4 v = *(const float4*)(wbase + (long)row * kC + kc + seg * 4);
            ushort4 u = {f2b(v.x), f2b(v.y), f2b(v.z), f2b(v.w)};
            *(ushort4*)&Ws[row * 40 + seg * 4] = u;
        }
        // stage X: 64 rows x 32 k (bf16 copy)
        {
            int row = t >> 2, seg = t & 3;  // 4 segs of 8 bf16
            uint4 v = *(const uint4*)(xTb + (long)row * kC + kc + seg * 8);
            *(uint4*)&Xs[row * 40 + seg * 8] = v;
        }
        __syncthreads();
        bf16x8 a[2], bb[4];
#pragma unroll
        for (int mt = 0; mt < 2; mt++)
            a[mt] = *(const bf16x8*)&Ws[(32 * w + 16 * mt + ln) * 40 + q * 8];
#pragma unroll
        for (int nt = 0; nt < 4; nt++)
            bb[nt] = *(const bf16x8*)&Xs[(16 * nt + ln) * 40 + q * 8];
#pragma unroll
        for (int mt = 0; mt < 2; mt++)
#pragma unroll
            for (int nt = 0; nt < 4; nt++)
                acc[mt][nt] = __builtin_amdgcn_mfma_f32_16x16x32_bf16(
                    a[mt], bb[nt], acc[mt][nt], 0, 0, 0);
    }
    // D layout: col = lane&15, row = quad*4 + reg  [m89-verified]
    ushort* pb = PGh + (long)b * kC * kN;
#pragma unroll
    for (int mt = 0; mt < 2; mt++)
#pragma unroll
        for (int nt = 0; nt < 4; nt++)
#pragma unroll
            for (int i = 0; i < 4; i++) {
                int row = r0 + 32 * w + 16 * mt + 4 * q + i;
                int col = n0 + 16 * nt + ln;
                pb[(long)row * kN + col] = f2b(acc[mt][nt][i]);
            }
}

// ---- rs[b][r] = sum over n of PG[b][r][n]  (bf16 in, fp32 out) ------------
__global__ void rowsum_kernel(const ushort* __restrict__ PGh, float* __restrict__ rs) {
    int br = blockIdx.x;  // 0 .. kB*kC-1
    const ushort* p = PGh + (long)br * kN;
    float s = 0.f;
    for (int i = threadIdx.x * 8; i < kN; i += 2048) {
        uint4 v = *(const uint4*)(p + i);
        unsigned ww[4] = {v.x, v.y, v.z, v.w};
#pragma unroll
        for (int j = 0; j < 4; j++) {
            s += __uint_as_float(ww[j] << 16);
            s += __uint_as_float(ww[j] & 0xFFFF0000u);
        }
    }
    __shared__ float sm[256];
    sm[threadIdx.x] = s;
    __syncthreads();
    for (int st = 128; st > 0; st >>= 1) {
        if (threadIdx.x < st) sm[threadIdx.x] += sm[threadIdx.x + st];
        __syncthreads();
    }
    if (threadIdx.x == 0) rs[br] = sm[0];
}

// ---- Tpart[b][s] quadrant = Phi[rows, slice] * G2[rows, slice]^T via MFMA -
// Block: 64x64 quadrant; 4 waves, each 16(c) x 64(c') = 4 MFMA tiles. K=256.
__global__ void __launch_bounds__(256, 4)
tsplit_mfma(const ushort* __restrict__ PGh, float* __restrict__ Tpart) {
    int s = blockIdx.x, b = blockIdx.z;
    int qy = blockIdx.y >> 1, qx = blockIdx.y & 1;
    long nbase = (long)s * kSliceN;
    __shared__ ushort As[64 * 40];  // [row][k] bf16 (Phi rows)
    __shared__ ushort Bs[64 * 40];  // [row][k] bf16 (G2 rows)
    int t = threadIdx.x;
    int w = t >> 6, lane = t & 63, q = lane >> 4, ln = lane & 15;
    f32x4 acc[4];
#pragma unroll
    for (int j = 0; j < 4; j++) acc[j] = 0.f;
    const ushort* Phi = PGh + ((long)b * kC + 64 * qy) * kN + nbase;
    const ushort* G2  = PGh + ((long)b * kC + kCI + 64 * qx) * kN + nbase;
    for (int kc = 0; kc < kSliceN; kc += 32) {
        __syncthreads();
        {   // stage 64 rows x 32 k each (16B per thread, coalesced)
            int row = t >> 2, seg = t & 3;
            *(uint4*)&As[row * 40 + seg * 8] =
                *(const uint4*)(Phi + (long)row * kN + kc + seg * 8);
            *(uint4*)&Bs[row * 40 + seg * 8] =
                *(const uint4*)(G2 + (long)row * kN + kc + seg * 8);
        }
        __syncthreads();
        bf16x8 a = *(const bf16x8*)&As[(16 * w + ln) * 40 + q * 8];
#pragma unroll
        for (int nt = 0; nt < 4; nt++) {
            bf16x8 bb = *(const bf16x8*)&Bs[(16 * nt + ln) * 40 + q * 8];
            acc[nt] = __builtin_amdgcn_mfma_f32_16x16x32_bf16(a, bb, acc[nt], 0, 0, 0);
        }
    }
    float* Tp = Tpart + ((long)b * kSplits + s) * kCI * kCI;
#pragma unroll
    for (int nt = 0; nt < 4; nt++)
#pragma unroll
        for (int i = 0; i < 4; i++) {
            int c  = 64 * qy + 16 * w + 4 * q + i;
            int cp = 64 * qx + 16 * nt + ln;
            Tp[(long)c * kCI + cp] = acc[nt][i];
        }
}

// ---- T[b] = sum_s Tpart[b][s] - rsPhi*rsG2^T/N ----------------------------
__global__ void treduce_kernel(const float* __restrict__ Tpart, const float* __restrict__ rs,
                               float* __restrict__ T) {
    int idx = blockIdx.x * 256 + threadIdx.x;
    int b = idx >> 14;
    int c = (idx >> 7) & 127, cp = idx & 127;
    const float* tp = Tpart + (long)b * kSplits * kCI * kCI + (idx & 16383);
    float s = 0.f;
#pragma unroll
    for (int sl = 0; sl < kSplits; sl++) s += tp[(long)sl * kCI * kCI];
    s -= rs[b * kC + c] * rs[b * kC + kCI + cp] * (1.f / kN);
    T[idx] = s;
}

// ---- NT gemm, 64x64 tile, 4x4/thread --------------------------------------
__global__ void __launch_bounds__(256, 4)
nt64_gemm(const float* __restrict__ A, const float* __restrict__ B,
          float* __restrict__ Cm, int M, int N, int K,
          long sA, long sB, long sC) {
    int b = blockIdx.z;
    const float* Ab = A + (long)b * sA;
    const float* Bb = B + (long)b * sB;
    float* Cb = Cm + (long)b * sC;
    __shared__ __align__(16) float As[16][68];
    __shared__ __align__(16) float Bs[16][68];
    int t = threadIdx.x;
    int tx = t & 15, ty = t >> 4;
    int m0 = blockIdx.y * 64, n0 = blockIdx.x * 64;
    float acc[4][4] = {};
    for (int kc = 0; kc < K; kc += 16) {
        __syncthreads();
        {
            int r = t >> 2, c4 = (t & 3) * 4;
            float4 va = *(const float4*)(Ab + (long)(m0 + r) * K + kc + c4);
            As[c4 + 0][r] = va.x; As[c4 + 1][r] = va.y;
            As[c4 + 2][r] = va.z; As[c4 + 3][r] = va.w;
            float4 vb = *(const float4*)(Bb + (long)(n0 + r) * K + kc + c4);
            Bs[c4 + 0][r] = vb.x; Bs[c4 + 1][r] = vb.y;
            Bs[c4 + 2][r] = vb.z; Bs[c4 + 3][r] = vb.w;
        }
        __syncthreads();
#pragma unroll
        for (int k = 0; k < 16; k++) {
            float4 a = *(const float4*)&As[k][4 * ty];
            float4 bv = *(const float4*)&Bs[k][4 * tx];
            float av[4] = {a.x, a.y, a.z, a.w};
            float bw[4] = {bv.x, bv.y, bv.z, bv.w};
#pragma unroll
            for (int i = 0; i < 4; i++)
#pragma unroll
                for (int j = 0; j < 4; j++) acc[i][j] += av[i] * bw[j];
        }
    }
#pragma unroll
    for (int i = 0; i < 4; i++) {
        float4 ov = {acc[i][0], acc[i][1], acc[i][2], acc[i][3]};
        *(float4*)(Cb + (long)(m0 + 4 * ty + i) * N + n0 + 4 * tx) = ov;
    }
}

// ---- beta[b,o] = out_b[o] + sum_k theta_bc[k] * W2t[b,o,k] ----------------
__global__ void beta_kernel(const float* __restrict__ W2t, const float* __restrict__ tbc,
                            const float* __restrict__ out_b, float* __restrict__ beta) {
    int i = blockIdx.x * blockDim.x + threadIdx.x;
    if (i >= kB * kC) return;
    int o = i & (kC - 1);
    float s = out_b[o];
    const float* row = W2t + (long)i * kCI;
#pragma unroll 8
    for (int k = 0; k < kCI; k++) s += tbc[k] * row[k];
    beta[i] = s;
}

// ---- out = x + Mt(bf16) x xT(bf16) + beta  via MFMA -----------------------
__global__ void __launch_bounds__(256, 2)
final_mfma(const float* __restrict__ x, const float* __restrict__ Mt,
           const ushort* __restrict__ xT, const float* __restrict__ beta,
           float* __restrict__ out) {
    int b = blockIdx.z;
    int o0 = blockIdx.y * 128, n0 = blockIdx.x * 64;
    const float* Mb = Mt + (long)b * kC * kC;
    __shared__ ushort Ws[128 * 40];
    __shared__ ushort Xs[64 * 40];
    int t = threadIdx.x;
    int w = t >> 6, lane = t & 63, q = lane >> 4, ln = lane & 15;
    f32x4 acc[2][4];
#pragma unroll
    for (int i = 0; i < 2; i++)
#pragma unroll
        for (int j = 0; j < 4; j++) acc[i][j] = 0.f;
    const ushort* xTb = xT + ((long)b * kN + n0) * kC;
    for (int kc = 0; kc < kC; kc += 32) {
        __syncthreads();
#pragma unroll
        for (int it = 0; it < 4; it++) {
            int l = t + 256 * it;
            int row = l >> 3, seg = l & 7;
            float4 v = *(const float4*)(Mb + (long)(o0 + row) * kC + kc + seg * 4);
            ushort4 u = {f2b(v.x), f2b(v.y), f2b(v.z), f2b(v.w)};
            *(ushort4*)&Ws[row * 40 + seg * 4] = u;
        }
        {
            int row = t >> 2, seg = t & 3;
            uint4 v = *(const uint4*)(xTb + (long)row * kC + kc + seg * 8);
            *(uint4*)&Xs[row * 40 + seg * 8] = v;
        }
        __syncthreads();
        bf16x8 a[2], bb[4];
#pragma unroll
        for (int mt = 0; mt < 2; mt++)
            a[mt] = *(const bf16x8*)&Ws[(32 * w + 16 * mt + ln) * 40 + q * 8];
#pragma unroll
        for (int nt = 0; nt < 4; nt++)
            bb[nt] = *(const bf16x8*)&Xs[(16 * nt + ln) * 40 + q * 8];
#pragma unroll
        for (int mt = 0; mt < 2; mt++)
#pragma unroll
            for (int nt = 0; nt < 4; nt++)
                acc[mt][nt] = __builtin_amdgcn_mfma_f32_16x16x32_bf16(
                    a[mt], bb[nt], acc[mt][nt], 0, 0, 0);
    }
    const float* xb = x + (long)b * kC * kN;
    float* ob = out + (long)b * kC * kN;
#pragma unroll
    for (int mt = 0; mt < 2; mt++)
#pragma unroll
        for (int nt = 0; nt < 4; nt++)
#pragma unroll
            for (int i = 0; i < 4; i++) {
                int row = o0 + 32 * w + 16 * mt + 4 * q + i;
                int col = n0 + 16 * nt + ln;
                long idx = (long)row * kN + col;
                ob[idx] = acc[mt][nt][i] + xb[idx] + beta[b * kC + row];
            }
}

extern "C" void kernel_launch(void* const* d_in, const int* in_sizes, int n_in,
                              void* d_out, int out_size, void* d_ws, size_t ws_size,
                              hipStream_t stream) {
    const float* x       = (const float*)d_in[0];
    const float* g_w     = (const float*)d_in[1];
    // d_in[2] = g_b   : cancelled (rows of Phic sum to 0)
    const float* theta_w = (const float*)d_in[3];
    const float* theta_b = (const float*)d_in[4];
    const float* phi_w   = (const float*)d_in[5];
    // d_in[6] = phi_b : cancelled by spatial centering
    const float* out_w   = (const float*)d_in[7];
    const float* out_b   = (const float*)d_in[8];
    float* out = (float*)d_out;
    float* ws  = (float*)d_ws;  // needs ~23 MB

    float*  twcT  = ws + kOffTwcT;
    float*  tbc   = ws + kOffTbc;
    ushort* PGh   = (ushort*)(ws + kOffPG);
    float*  rs    = ws + kOffRs;
    float*  Tpart = ws + kOffTpart;
    float*  T     = ws + kOffT;
    float*  W2t   = ws + kOffW2t;
    float*  Mt    = ws + kOffMt;
    float*  beta  = ws + kOffBeta;
    ushort* xT    = (ushort*)(ws + kOffXT);

    // xT[b][n][c] = bf16(x[b][c][n])
    xt_kernel<<<dim3(kN / 64, kC / 64, kB), 256, 0, stream>>>(x, xT);
    centerw_kernel<<<1, 256, 0, stream>>>(theta_w, theta_b, twcT, tbc);
    // PG[b] = [phi_w; g_w] * X[b]   (MFMA bf16 in/out)
    pg_mfma<<<dim3(kN / 64, 2, kB), 256, 0, stream>>>(phi_w, g_w, xT, PGh);
    rowsum_kernel<<<kB * kC, 256, 0, stream>>>(PGh, rs);
    // Tpart[b][s] = Phi_slice * G2_slice^T  (MFMA bf16, quadrant per block)
    tsplit_mfma<<<dim3(kSplits, 4, kB), 256, 0, stream>>>(PGh, Tpart);
    treduce_kernel<<<kB * kCI * kCI / 256, 256, 0, stream>>>(Tpart, rs, T);
    // W2t[b] = out_w * T[b]^T       (M=256, N=128, K=128)
    nt64_gemm<<<dim3(2, 4, kB), 256, 0, stream>>>(out_w, T, W2t, kC, kCI, kCI,
                                                  0, (long)kCI * kCI, (long)kC * kCI);
    // Mt[b] = W2t[b] * theta_wc     (M=256, N=256, K=128)
    nt64_gemm<<<dim3(4, 4, kB), 256, 0, stream>>>(W2t, twcT, Mt, kC, kC, kCI,
                                                  (long)kC * kCI, 0, (long)kC * kC);
    beta_kernel<<<kB, 256, 0, stream>>>(W2t, tbc, out_b, beta);
    // out = x + Mt * X + beta       (MFMA bf16 + fp32 residual epilogue)
    final_mfma<<<dim3(kN / 64, 2, kB), 256, 0, stream>>>(x, Mt, xT, beta, out);
}